// Round 3
// baseline (119.102 us; speedup 1.0000x reference)
//
#include <hip/hip_runtime.h>

#define DIM    256
#define NROWS  8192
#define NHALF  4096
#define NTILE  64                          // 8192 / 128 tiles per dim
#define NBLK   ((NTILE * (NTILE + 1)) / 2) // 2080 triangular tiles

using i32x4  = __attribute__((ext_vector_type(4))) int;
using i32x8  = __attribute__((ext_vector_type(8))) int;
using f32x16 = __attribute__((ext_vector_type(16))) float;

struct i32x8_pair { i32x4 lo, hi; };

// ---- kernel 1: row-normalize x (fp32) -> z8 (fp8 e4m3), one wave per row.
// Block 0 also zeroes the accumulators + completion counter (ws is poisoned).
__global__ __launch_bounds__(256) void normalize_k(const float* __restrict__ x,
                                                   unsigned char* __restrict__ z8,
                                                   double* __restrict__ acc) {
  if (blockIdx.x == 0) {
    if (threadIdx.x < 2) acc[threadIdx.x] = 0.0;
    if (threadIdx.x == 2) ((int*)(acc + 2))[0] = 0;
  }
  const int row  = blockIdx.x * 4 + (threadIdx.x >> 6);
  const int lane = threadIdx.x & 63;
  float4 v = ((const float4*)(x + (size_t)row * DIM))[lane];
  float ss = v.x * v.x + v.y * v.y + v.z * v.z + v.w * v.w;
#pragma unroll
  for (int off = 32; off > 0; off >>= 1) ss += __shfl_xor(ss, off, 64);
  float rn = rsqrtf(fmaxf(ss, 1e-24f));
  int p = __builtin_amdgcn_cvt_pk_fp8_f32(v.x * rn, v.y * rn, 0, false);
  p     = __builtin_amdgcn_cvt_pk_fp8_f32(v.z * rn, v.w * rn, p, true);
  ((int*)(z8 + (size_t)row * DIM))[lane] = p;
}

// ---- kernel 2: Gram exp-sum over upper-triangular 128x128 tiles, MX-fp8.
// Single K=256 staging round; fused sim_s diagonal; fused last-block finalize.
__global__ __launch_bounds__(256, 2) void gram_k(const unsigned char* __restrict__ z8,
                                                 double* __restrict__ acc,
                                                 float* __restrict__ out) {
  __shared__ unsigned char As[128 * 256];   // 32 KB
  __shared__ unsigned char Bs[128 * 256];   // 32 KB
  __shared__ float red[8];

  // linear block id -> (bi, bj), bi <= bj
  const int bid = blockIdx.x;
  int bi = (int)((129.0 - sqrt(129.0 * 129.0 - 8.0 * (double)bid)) * 0.5);
  while ((bi * (129 - bi)) / 2 > bid) --bi;
  while (((bi + 1) * (128 - bi)) / 2 <= bid) ++bi;
  const int bj = bi + (bid - (bi * (129 - bi)) / 2);

  const int tid   = threadIdx.x;
  const int lane  = tid & 63;
  const int w     = tid >> 6;
  const int wr    = w >> 1, wc = w & 1;     // 2x2 wave grid, 64x64 each
  const int l31   = lane & 31;
  const int khalf = lane >> 5;              // K-half selector for 32x32 frags

  const size_t rowA0 = (size_t)bi * 128;
  const size_t rowB0 = (size_t)bj * 128;

  // stage full 128x256B A and B tiles via global_load_lds, 16B/lane.
  // LDS 16B-chunk cb holds global chunk (cb&8) | ((cb&7) ^ (row&7))
  // (swizzle on the global side: glds dest = wave-uniform base + lane*16).
#pragma unroll
  for (int i = 0; i < 8; ++i) {
    int c   = i * 256 + tid;                // 0..2047 -> (row, chunk)
    int row = c >> 4;                       // 0..127
    int cb  = c & 15;
    int gcb = (cb & 8) | ((cb & 7) ^ (row & 7));
    const unsigned char* ga = z8 + (rowA0 + row) * DIM + gcb * 16;
    const unsigned char* gb = z8 + (rowB0 + row) * DIM + gcb * 16;
    __builtin_amdgcn_global_load_lds(
        (const __attribute__((address_space(1))) void*)ga,
        (__attribute__((address_space(3))) void*)&As[(size_t)(i * 256 + (tid & ~63)) * 16],
        16, 0, 0);
    __builtin_amdgcn_global_load_lds(
        (const __attribute__((address_space(1))) void*)gb,
        (__attribute__((address_space(3))) void*)&Bs[(size_t)(i * 256 + (tid & ~63)) * 16],
        16, 0, 0);
  }
  __syncthreads();

  f32x16 acc_f[2][2] = {};
#pragma unroll
  for (int kc = 0; kc < 4; ++kc) {          // four K=64 MFMA chunks
    const int cb0 = kc * 4 + khalf * 2;     // even; +1 stays in same 8-group
    i32x8 a[2], b[2];
#pragma unroll
    for (int t = 0; t < 2; ++t) {
      int mr = wr * 64 + t * 32 + l31;
      int c0 = (cb0 & 8) | ((cb0 & 7) ^ (mr & 7));
      int c1 = c0 ^ 1 ^ 0;                  // (cb0+1) swizzled: flips bit0 only
      c1 = (cb0 & 8) | (((cb0 + 1) & 7) ^ (mr & 7));
      i32x8_pair pa = { *(const i32x4*)&As[mr * 256 + c0 * 16],
                        *(const i32x4*)&As[mr * 256 + c1 * 16] };
      a[t] = __builtin_bit_cast(i32x8, pa);
      int nr = wc * 64 + t * 32 + l31;
      int d0 = (cb0 & 8) | ((cb0 & 7) ^ (nr & 7));
      int d1 = (cb0 & 8) | (((cb0 + 1) & 7) ^ (nr & 7));
      i32x8_pair pb = { *(const i32x4*)&Bs[nr * 256 + d0 * 16],
                        *(const i32x4*)&Bs[nr * 256 + d1 * 16] };
      b[t] = __builtin_bit_cast(i32x8, pb);
    }
#pragma unroll
    for (int ti = 0; ti < 2; ++ti)
#pragma unroll
      for (int tj = 0; tj < 2; ++tj)
        acc_f[ti][tj] = __builtin_amdgcn_mfma_scale_f32_32x32x64_f8f6f4(
            a[ti], b[tj], acc_f[ti][tj],
            0, 0,                           // fp8 e4m3 A and B
            0, 0x7f7f7f7f,                  // scale_a = 1.0 (E8M0 127)
            0, 0x7f7f7f7f);                 // scale_b = 1.0
  }

  // epilogue: exp(cos/TEMP), TEMP = 2. Uniform-branch diagonal handling.
  const bool tdiag = (bi == bj);            // true diagonal tile
  const bool sdiag = (bj == bi + 32);       // (i, i+4096) sim_s tile
  float lsum = 0.0f, dsum = 0.0f;
  if (tdiag || sdiag) {
#pragma unroll
    for (int ti = 0; ti < 2; ++ti)
#pragma unroll
      for (int tj = 0; tj < 2; ++tj)
#pragma unroll
        for (int r = 0; r < 16; ++r) {
          float e = __expf(acc_f[ti][tj][r] * 0.5f);
          lsum += e;
          int row_l = (r & 3) + 8 * (r >> 2) + 4 * khalf;
          if (wr == wc && ti == tj && row_l == l31) dsum += e;
        }
  } else {
#pragma unroll
    for (int ti = 0; ti < 2; ++ti)
#pragma unroll
      for (int tj = 0; tj < 2; ++tj)
#pragma unroll
        for (int r = 0; r < 16; ++r)
          lsum += __expf(acc_f[ti][tj][r] * 0.5f);
  }
#pragma unroll
  for (int off = 32; off > 0; off >>= 1) lsum += __shfl_xor(lsum, off, 64);
  if (tdiag || sdiag) {
#pragma unroll
    for (int off = 32; off > 0; off >>= 1) dsum += __shfl_xor(dsum, off, 64);
  }
  if (lane == 0) { red[w] = lsum; red[4 + w] = dsum; }
  __syncthreads();

  if (tid == 0) {
    float l  = red[0] + red[1] + red[2] + red[3];
    float dd = red[4] + red[5] + red[6] + red[7];
    // acc[0] accumulates T_full + all_diag: diag tile = lsum + extra diag,
    // off-diag tile counts twice by symmetry.
    double c0 = tdiag ? (double)l + (double)dd : 2.0 * (double)l;
    atomicAdd(acc, c0);
    if (sdiag) atomicAdd(acc + 1, (double)dd);
    __threadfence();
    int done = atomicAdd((int*)(acc + 2), 1);
    if (done == NBLK - 1) {                 // last block finalizes
      __threadfence();
      double S  = atomicAdd(acc, 0.0);      // coherent RMW read
      double ss = atomicAdd(acc + 1, 0.0);
      out[0] = (float)(log(0.5 * S + ss) - log(ss));
    }
  }
}

extern "C" void kernel_launch(void* const* d_in, const int* in_sizes, int n_in,
                              void* d_out, int out_size, void* d_ws, size_t ws_size,
                              hipStream_t stream) {
  const float* x    = (const float*)d_in[0];
  unsigned char* z8 = (unsigned char*)d_ws;                 // 8192*256 fp8 = 2 MB
  double* acc       = (double*)((char*)d_ws + (size_t)NROWS * DIM);
  float* out        = (float*)d_out;

  normalize_k<<<dim3(NROWS / 4), dim3(256), 0, stream>>>(x, z8, acc);
  gram_k<<<dim3(NBLK), dim3(256), 0, stream>>>(z8, acc, out);
}

// Round 4
// 101.043 us; speedup vs baseline: 1.1787x; 1.1787x over previous
//
#include <hip/hip_runtime.h>

#define DIM    256
#define NROWS  8192
#define NHALF  4096
#define NTILE  64                          // 8192 / 128 tiles per dim
#define NBLK   ((NTILE * (NTILE + 1)) / 2) // 2080 triangular tiles
#define NSLOT  32                          // spread slots for main accumulator

using i32x4  = __attribute__((ext_vector_type(4))) int;
using i32x8  = __attribute__((ext_vector_type(8))) int;
using f32x16 = __attribute__((ext_vector_type(16))) float;

struct i32x8_pair { i32x4 lo, hi; };

// ws layout after z8 (2 MB): 32 f64 slots at 64B stride, then sim_s line,
// then counter line.
#define SLOT_D(base, i) ((double*)((char*)(base) + (size_t)(i) * 64))
#define SSUM_D(base)    ((double*)((char*)(base) + (size_t)NSLOT * 64))
#define CNT_I(base)     ((int*)((char*)(base) + (size_t)NSLOT * 64 + 64))

// ---- kernel 1: row-normalize x (fp32) -> z8 (fp8 e4m3), one wave per row.
// Block 0 also zeroes the slots / sim_s / counter (ws is poisoned each call).
__global__ __launch_bounds__(256) void normalize_k(const float* __restrict__ x,
                                                   unsigned char* __restrict__ z8,
                                                   void* __restrict__ accbase) {
  if (blockIdx.x == 0) {
    int t = threadIdx.x;
    if (t < NSLOT)       *SLOT_D(accbase, t) = 0.0;
    else if (t == NSLOT) *SSUM_D(accbase)    = 0.0;
    else if (t == NSLOT + 1) *CNT_I(accbase) = 0;
  }
  const int row  = blockIdx.x * 4 + (threadIdx.x >> 6);
  const int lane = threadIdx.x & 63;
  float4 v = ((const float4*)(x + (size_t)row * DIM))[lane];
  float ss = v.x * v.x + v.y * v.y + v.z * v.z + v.w * v.w;
#pragma unroll
  for (int off = 32; off > 0; off >>= 1) ss += __shfl_xor(ss, off, 64);
  float rn = rsqrtf(fmaxf(ss, 1e-24f));
  int p = __builtin_amdgcn_cvt_pk_fp8_f32(v.x * rn, v.y * rn, 0, false);
  p     = __builtin_amdgcn_cvt_pk_fp8_f32(v.z * rn, v.w * rn, p, true);
  ((int*)(z8 + (size_t)row * DIM))[lane] = p;
}

// ---- kernel 2: Gram exp-sum over upper-triangular 128x128 tiles, MX-fp8.
// Two K=128 staging rounds (32 KB LDS, 3 blocks/CU). Fused sim_s diagonal
// and fence-free last-block finalize.
__global__ __launch_bounds__(256, 3) void gram_k(const unsigned char* __restrict__ z8,
                                                 void* __restrict__ accbase,
                                                 float* __restrict__ out) {
  __shared__ unsigned char As[128 * 128];   // 16 KB
  __shared__ unsigned char Bs[128 * 128];   // 16 KB
  __shared__ float red[8];

  // linear block id -> (bi, bj), bi <= bj
  const int bid = blockIdx.x;
  int bi = (int)((129.0 - sqrt(129.0 * 129.0 - 8.0 * (double)bid)) * 0.5);
  while ((bi * (129 - bi)) / 2 > bid) --bi;
  while (((bi + 1) * (128 - bi)) / 2 <= bid) ++bi;
  const int bj = bi + (bid - (bi * (129 - bi)) / 2);

  const int tid   = threadIdx.x;
  const int lane  = tid & 63;
  const int w     = tid >> 6;
  const int wr    = w >> 1, wc = w & 1;     // 2x2 wave grid, 64x64 each
  const int l31   = lane & 31;
  const int khalf = lane >> 5;              // K-half selector for 32x32 frags

  const size_t rowA0 = (size_t)bi * 128;
  const size_t rowB0 = (size_t)bj * 128;

  f32x16 acc_f[2][2] = {};

  for (int kb = 0; kb < 2; ++kb) {          // two BK=128 staging rounds
    // stage 128 rows x 128 fp8 bytes for A and B via global_load_lds, 16B/lane.
    // LDS colblock cb holds global colblock cb ^ (row&7) (swizzle applied on
    // the global side: glds forces dest = wave-uniform base + lane*16).
#pragma unroll
    for (int i = 0; i < 4; ++i) {
      int c   = i * 256 + tid;              // 0..1023 -> (row, colblock)
      int row = c >> 3;                     // 0..127
      int cb  = c & 7;
      int gcb = cb ^ (row & 7);
      const unsigned char* ga = z8 + (rowA0 + row) * DIM + kb * 128 + gcb * 16;
      const unsigned char* gb = z8 + (rowB0 + row) * DIM + kb * 128 + gcb * 16;
      __builtin_amdgcn_global_load_lds(
          (const __attribute__((address_space(1))) void*)ga,
          (__attribute__((address_space(3))) void*)&As[(size_t)(i * 256 + (tid & ~63)) * 16],
          16, 0, 0);
      __builtin_amdgcn_global_load_lds(
          (const __attribute__((address_space(1))) void*)gb,
          (__attribute__((address_space(3))) void*)&Bs[(size_t)(i * 256 + (tid & ~63)) * 16],
          16, 0, 0);
    }
    __syncthreads();

#pragma unroll
    for (int kc = 0; kc < 2; ++kc) {        // two K=64 MFMA chunks per round
      i32x8 a[2], b[2];
#pragma unroll
      for (int t = 0; t < 2; ++t) {
        const int cb0 = kc * 4 + khalf * 2; // first 16B colblock of lane's 32B
        int mr = wr * 64 + t * 32 + l31;
        i32x8_pair pa = { *(const i32x4*)&As[mr * 128 + ((cb0    ) ^ (mr & 7)) * 16],
                          *(const i32x4*)&As[mr * 128 + ((cb0 + 1) ^ (mr & 7)) * 16] };
        a[t] = __builtin_bit_cast(i32x8, pa);
        int nr = wc * 64 + t * 32 + l31;
        i32x8_pair pb = { *(const i32x4*)&Bs[nr * 128 + ((cb0    ) ^ (nr & 7)) * 16],
                          *(const i32x4*)&Bs[nr * 128 + ((cb0 + 1) ^ (nr & 7)) * 16] };
        b[t] = __builtin_bit_cast(i32x8, pb);
      }
#pragma unroll
      for (int ti = 0; ti < 2; ++ti)
#pragma unroll
        for (int tj = 0; tj < 2; ++tj)
          acc_f[ti][tj] = __builtin_amdgcn_mfma_scale_f32_32x32x64_f8f6f4(
              a[ti], b[tj], acc_f[ti][tj],
              0, 0,                         // fp8 e4m3 A and B
              0, 0x7f7f7f7f,                // scale_a = 1.0 (E8M0 127)
              0, 0x7f7f7f7f);               // scale_b = 1.0
    }
    __syncthreads();
  }

  // epilogue: exp(cos/TEMP), TEMP = 2. Uniform-branch diagonal handling.
  const bool tdiag = (bi == bj);            // true diagonal tile
  const bool sdiag = (bj == bi + 32);       // (i, i+4096) sim_s tile
  float lsum = 0.0f, dsum = 0.0f;
  if (tdiag || sdiag) {
#pragma unroll
    for (int ti = 0; ti < 2; ++ti)
#pragma unroll
      for (int tj = 0; tj < 2; ++tj)
#pragma unroll
        for (int r = 0; r < 16; ++r) {
          float e = __expf(acc_f[ti][tj][r] * 0.5f);
          lsum += e;
          // 32x32 C/D: col = lane&31, row = (reg&3) + 8*(reg>>2) + 4*khalf
          int row_l = (r & 3) + 8 * (r >> 2) + 4 * khalf;
          if (wr == wc && ti == tj && row_l == l31) dsum += e;
        }
  } else {
#pragma unroll
    for (int ti = 0; ti < 2; ++ti)
#pragma unroll
      for (int tj = 0; tj < 2; ++tj)
#pragma unroll
        for (int r = 0; r < 16; ++r)
          lsum += __expf(acc_f[ti][tj][r] * 0.5f);
  }
#pragma unroll
  for (int off = 32; off > 0; off >>= 1) lsum += __shfl_xor(lsum, off, 64);
  if (tdiag || sdiag) {
#pragma unroll
    for (int off = 32; off > 0; off >>= 1) dsum += __shfl_xor(dsum, off, 64);
  }
  if (lane == 0) { red[w] = lsum; red[4 + w] = dsum; }
  __syncthreads();

  if (tid == 0) {
    float l  = red[0] + red[1] + red[2] + red[3];
    float dd = red[4] + red[5] + red[6] + red[7];
    // S accumulates T_full + all_diag: diag tile contributes lsum + diag
    // extra, off-diag tile counts twice by symmetry.
    double c0 = tdiag ? (double)l + (double)dd : 2.0 * (double)l;
    double old  = atomicAdd(SLOT_D(accbase, bid & (NSLOT - 1)), c0);
    double old2 = 0.0;
    if (sdiag) old2 = atomicAdd(SSUM_D(accbase), (double)dd);
    // fence-free ordering: counter operand data-depends on the returned old
    // values, so the counter RMW issues only after the data RMWs completed
    // at the device coherence point.
    int bump = 1 + (int)((old + old2) * 0.0);
    int done = atomicAdd(CNT_I(accbase), bump);
    if (done == NBLK - 1) {                 // last completer finalizes
      double S = 0.0;
#pragma unroll
      for (int i = 0; i < NSLOT; ++i) S += atomicAdd(SLOT_D(accbase, i), 0.0);
      double ss = atomicAdd(SSUM_D(accbase), 0.0);
      out[0] = (float)(log(0.5 * S + ss) - log(ss));
    }
  }
}

extern "C" void kernel_launch(void* const* d_in, const int* in_sizes, int n_in,
                              void* d_out, int out_size, void* d_ws, size_t ws_size,
                              hipStream_t stream) {
  const float* x    = (const float*)d_in[0];
  unsigned char* z8 = (unsigned char*)d_ws;                 // 8192*256 fp8 = 2 MB
  void* accbase     = (void*)((char*)d_ws + (size_t)NROWS * DIM);
  float* out        = (float*)d_out;

  normalize_k<<<dim3(NROWS / 4), dim3(256), 0, stream>>>(x, z8, accbase);
  gram_k<<<dim3(NBLK), dim3(256), 0, stream>>>(z8, accbase, out);
}

// Round 5
// 78.446 us; speedup vs baseline: 1.5183x; 1.2881x over previous
//
#include <hip/hip_runtime.h>

#define DIM    256
#define NROWS  8192
#define NHALF  4096
#define NTILE  64                          // 8192 / 128 tiles per dim
#define NBLK   ((NTILE * (NTILE + 1)) / 2) // 2080 triangular tiles

using i32x4  = __attribute__((ext_vector_type(4))) int;
using i32x8  = __attribute__((ext_vector_type(8))) int;
using f32x16 = __attribute__((ext_vector_type(16))) float;

struct i32x8_pair { i32x4 lo, hi; };

// ---- kernel 1: row-normalize x (fp32) -> z8 (fp8 e4m3), one wave per row.
__global__ __launch_bounds__(256) void normalize_k(const float* __restrict__ x,
                                                   unsigned char* __restrict__ z8) {
  const int row  = blockIdx.x * 4 + (threadIdx.x >> 6);
  const int lane = threadIdx.x & 63;
  float4 v = ((const float4*)(x + (size_t)row * DIM))[lane];
  float ss = v.x * v.x + v.y * v.y + v.z * v.z + v.w * v.w;
#pragma unroll
  for (int off = 32; off > 0; off >>= 1) ss += __shfl_xor(ss, off, 64);
  float rn = rsqrtf(fmaxf(ss, 1e-24f));
  int p = __builtin_amdgcn_cvt_pk_fp8_f32(v.x * rn, v.y * rn, 0, false);
  p     = __builtin_amdgcn_cvt_pk_fp8_f32(v.z * rn, v.w * rn, p, true);
  ((int*)(z8 + (size_t)row * DIM))[lane] = p;
}

// ---- kernel 2: Gram exp-sum over upper-triangular 128x128 tiles, MX-fp8.
// NO atomics: each block writes its partial (c0, dsum) to a unique slot.
__global__ __launch_bounds__(256, 3) void gram_k(const unsigned char* __restrict__ z8,
                                                 double2* __restrict__ partial) {
  __shared__ unsigned char As[128 * 128];   // 16 KB
  __shared__ unsigned char Bs[128 * 128];   // 16 KB
  __shared__ float red[8];

  // linear block id -> (bi, bj), bi <= bj
  const int bid = blockIdx.x;
  int bi = (int)((129.0 - sqrt(129.0 * 129.0 - 8.0 * (double)bid)) * 0.5);
  while ((bi * (129 - bi)) / 2 > bid) --bi;
  while (((bi + 1) * (128 - bi)) / 2 <= bid) ++bi;
  const int bj = bi + (bid - (bi * (129 - bi)) / 2);

  const int tid   = threadIdx.x;
  const int lane  = tid & 63;
  const int w     = tid >> 6;
  const int wr    = w >> 1, wc = w & 1;     // 2x2 wave grid, 64x64 each
  const int l31   = lane & 31;
  const int khalf = lane >> 5;              // K-half selector for 32x32 frags

  const size_t rowA0 = (size_t)bi * 128;
  const size_t rowB0 = (size_t)bj * 128;

  f32x16 acc_f[2][2] = {};

  for (int kb = 0; kb < 2; ++kb) {          // two BK=128 staging rounds
    // stage 128 rows x 128 fp8 bytes for A and B via global_load_lds, 16B/lane.
    // LDS colblock cb holds global colblock cb ^ (row&7) (swizzle applied on
    // the global side: glds forces dest = wave-uniform base + lane*16).
#pragma unroll
    for (int i = 0; i < 4; ++i) {
      int c   = i * 256 + tid;              // 0..1023 -> (row, colblock)
      int row = c >> 3;                     // 0..127
      int cb  = c & 7;
      int gcb = cb ^ (row & 7);
      const unsigned char* ga = z8 + (rowA0 + row) * DIM + kb * 128 + gcb * 16;
      const unsigned char* gb = z8 + (rowB0 + row) * DIM + kb * 128 + gcb * 16;
      __builtin_amdgcn_global_load_lds(
          (const __attribute__((address_space(1))) void*)ga,
          (__attribute__((address_space(3))) void*)&As[(size_t)(i * 256 + (tid & ~63)) * 16],
          16, 0, 0);
      __builtin_amdgcn_global_load_lds(
          (const __attribute__((address_space(1))) void*)gb,
          (__attribute__((address_space(3))) void*)&Bs[(size_t)(i * 256 + (tid & ~63)) * 16],
          16, 0, 0);
    }
    __syncthreads();

#pragma unroll
    for (int kc = 0; kc < 2; ++kc) {        // two K=64 MFMA chunks per round
      i32x8 a[2], b[2];
#pragma unroll
      for (int t = 0; t < 2; ++t) {
        const int cb0 = kc * 4 + khalf * 2; // first 16B colblock of lane's 32B
        int mr = wr * 64 + t * 32 + l31;
        i32x8_pair pa = { *(const i32x4*)&As[mr * 128 + ((cb0    ) ^ (mr & 7)) * 16],
                          *(const i32x4*)&As[mr * 128 + ((cb0 + 1) ^ (mr & 7)) * 16] };
        a[t] = __builtin_bit_cast(i32x8, pa);
        int nr = wc * 64 + t * 32 + l31;
        i32x8_pair pb = { *(const i32x4*)&Bs[nr * 128 + ((cb0    ) ^ (nr & 7)) * 16],
                          *(const i32x4*)&Bs[nr * 128 + ((cb0 + 1) ^ (nr & 7)) * 16] };
        b[t] = __builtin_bit_cast(i32x8, pb);
      }
#pragma unroll
      for (int ti = 0; ti < 2; ++ti)
#pragma unroll
        for (int tj = 0; tj < 2; ++tj)
          acc_f[ti][tj] = __builtin_amdgcn_mfma_scale_f32_32x32x64_f8f6f4(
              a[ti], b[tj], acc_f[ti][tj],
              0, 0,                         // fp8 e4m3 A and B
              0, 0x7f7f7f7f,                // scale_a = 1.0 (E8M0 127)
              0, 0x7f7f7f7f);               // scale_b = 1.0
    }
    __syncthreads();
  }

  // epilogue: exp(cos/TEMP), TEMP = 2. Uniform-branch diagonal handling.
  const bool tdiag = (bi == bj);            // true diagonal tile
  const bool sdiag = (bj == bi + 32);       // (i, i+4096) sim_s tile
  float lsum = 0.0f, dsum = 0.0f;
  if (tdiag || sdiag) {
#pragma unroll
    for (int ti = 0; ti < 2; ++ti)
#pragma unroll
      for (int tj = 0; tj < 2; ++tj)
#pragma unroll
        for (int r = 0; r < 16; ++r) {
          float e = __expf(acc_f[ti][tj][r] * 0.5f);
          lsum += e;
          // 32x32 C/D: col = lane&31, row = (reg&3) + 8*(reg>>2) + 4*khalf
          int row_l = (r & 3) + 8 * (r >> 2) + 4 * khalf;
          if (wr == wc && ti == tj && row_l == l31) dsum += e;
        }
  } else {
#pragma unroll
    for (int ti = 0; ti < 2; ++ti)
#pragma unroll
      for (int tj = 0; tj < 2; ++tj)
#pragma unroll
        for (int r = 0; r < 16; ++r)
          lsum += __expf(acc_f[ti][tj][r] * 0.5f);
  }
#pragma unroll
  for (int off = 32; off > 0; off >>= 1) lsum += __shfl_xor(lsum, off, 64);
  if (tdiag || sdiag) {
#pragma unroll
    for (int off = 32; off > 0; off >>= 1) dsum += __shfl_xor(dsum, off, 64);
  }
  if (lane == 0) { red[w] = lsum; red[4 + w] = dsum; }
  __syncthreads();

  if (tid == 0) {
    float l  = red[0] + red[1] + red[2] + red[3];
    float dd = red[4] + red[5] + red[6] + red[7];
    // S accumulates T_full + all_diag: diag tile contributes lsum + diag
    // extra, off-diag tile counts twice by symmetry.
    double2 v;
    v.x = tdiag ? (double)l + (double)dd : 2.0 * (double)l;
    v.y = sdiag ? (double)dd : 0.0;
    partial[bid] = v;                       // unique slot: plain store, no RMW
  }
}

// ---- kernel 3: reduce 2080 partials, compute the loss. One block.
__global__ __launch_bounds__(256) void reduce_k(const double2* __restrict__ partial,
                                                float* __restrict__ out) {
  __shared__ double redS[4], redD[4];
  double s = 0.0, ss = 0.0;
  for (int i = threadIdx.x; i < NBLK; i += 256) {
    double2 v = partial[i];
    s += v.x; ss += v.y;
  }
#pragma unroll
  for (int off = 32; off > 0; off >>= 1) {
    s  += __shfl_xor(s,  off, 64);
    ss += __shfl_xor(ss, off, 64);
  }
  const int w = threadIdx.x >> 6;
  if ((threadIdx.x & 63) == 0) { redS[w] = s; redD[w] = ss; }
  __syncthreads();
  if (threadIdx.x == 0) {
    double S  = redS[0] + redS[1] + redS[2] + redS[3];
    double sd = redD[0] + redD[1] + redD[2] + redD[3];
    out[0] = (float)(log(0.5 * S + sd) - log(sd));
  }
}

extern "C" void kernel_launch(void* const* d_in, const int* in_sizes, int n_in,
                              void* d_out, int out_size, void* d_ws, size_t ws_size,
                              hipStream_t stream) {
  const float* x    = (const float*)d_in[0];
  unsigned char* z8 = (unsigned char*)d_ws;                  // 8192*256 fp8 = 2 MB
  double2* partial  = (double2*)((char*)d_ws + (size_t)NROWS * DIM);  // 2080 * 16 B
  float* out        = (float*)d_out;

  normalize_k<<<dim3(NROWS / 4), dim3(256), 0, stream>>>(x, z8);
  gram_k<<<dim3(NBLK), dim3(256), 0, stream>>>(z8, partial);
  reduce_k<<<dim3(1), dim3(256), 0, stream>>>(partial, out);
}